// Round 11
// baseline (245.831 us; speedup 1.0000x reference)
//
#include <hip/hip_runtime.h>
#include <hip/hip_bf16.h>

// B=4, N=1024, E=256, H=8, D=32. Float tensors may be bf16 OR fp32 in d_in /
// d_out (detected at runtime on-device); adj is int32.
// Output: x_out [4,1024,256] then e_out [4,1024,1024] (element offsets).
//
// ws float offsets:
//   [0 .. 196608)   : weight matrices, bf16, ushort offset m*65536, ALL o-major
//       W[o][e] at m*65536 + o*256 + e.  m: 0=Wcat 1=LIN 2=WQ 3=WK 4=WV 5=WO
#define BIAS_OFF 196608   // lin_b, bq, bk, bv, bo, a1, a2  (7*256 fp32)
#define S1_OFF   198400   // [h][4096]
#define S2_OFF   231168
#define CS_OFF   263936   // +4096: zero-bias[256] (setup-filled)
#define ST1_OFF  296704   // RAW col stats xa-norm: sum[4][256] + sumsq[4][256] (atomic)
#define ST2_OFF  298752   // RAW col stats lin-norm: sum + sumsq (atomic)
#define A_OFF    300800   // WhT bf16 [b][h][d][n] (2 MB) -> later Q,o fp32 head-major
#define MX_OFF   825088   // softmax row max [h][4096] (dead before Q overlays)
#define RS_OFF   857856   // softmax row 1/sum [h][4096]
#define PK_OFF   890624   // packed adj bitmask: [4096 rows][16 u64] (dead after eout8)
#define B_OFF    1349376  // 4 MB: rownorm(xa)     -> later K bf16 head-major [b][h][n][32]
#define C_OFF    2397952  // 4 MB: raw xa, then rownorm(lin) -> later V^T bf16 hm [b][h][d][n]
#define FLAG_F   3446528  // int: 1 = bf16 tensors, 0 = fp32 tensors
// end 3446529 floats = 13.8 MB

#define NEGC (-9.0e15f)

typedef __attribute__((ext_vector_type(8))) short bf16x8s;
typedef __attribute__((ext_vector_type(4))) float f32x4;

static __device__ __forceinline__ float bf2f(unsigned short u) {
  union { unsigned int i; float f; } v; v.i = ((unsigned int)u) << 16; return v.f;
}
static __device__ __forceinline__ unsigned short f2bf(float f) {
  union { float f; unsigned int u; } v; v.f = f;
  unsigned int r = (v.u + 0x7FFFu + ((v.u >> 16) & 1u)) >> 16;   // RNE
  return (unsigned short)r;
}
static __device__ __forceinline__ float ldin(const void* p, long i, int bf) {
  return bf ? bf2f(((const unsigned short*)p)[i]) : ((const float*)p)[i];
}
static __device__ __forceinline__ unsigned short rdbf(const void* p, long i, int bf) {
  if (bf) return ((const unsigned short*)p)[i];
  return f2bf(((const float*)p)[i]);
}
static __device__ __forceinline__ void stout(void* p, long i, float v, int bf) {
  if (bf) ((unsigned short*)p)[i] = f2bf(v);
  else    ((float*)p)[i] = v;
}

// ------- setup: detect(local) + weights o-major + biases + packadj + zero --
// Grid dim3(256, 8), block 256. Each block derives the dtype flag locally
// (wave-0 ballot on x) -- no cross-kernel dependency. m=0..5 weights,
// m=6: biases/zero-accs/flag-write, m=7: packadj 16 rows per block.
__global__ __launch_bounds__(256) void setup_kernel(
    const void* x, const void* wg, const void* lin_w, const void* inp_w,
    const void* out_w, const void* lin_b, const void* inp_b, const void* out_b,
    const void* a1, const void* a2, const int* adj, float* ws, int* flagp) {
  int t = threadIdx.x;
  int f = blockIdx.x;
  int m = blockIdx.y;
  __shared__ int bfs;
  if (t < 64) {
    unsigned short u = ((const unsigned short*)x)[2 * t];
    int e = (u >> 7) & 0xFF;
    bool good = (e >= 100 && e <= 140);
    unsigned long long msk = __ballot(good);
    if (t == 0) bfs = (__popcll(msk) >= 48) ? 1 : 0;
  }
  __syncthreads();
  const int bf = bfs;
  unsigned short* wbf = (unsigned short*)ws;
  if (m == 0) {
    int h = t >> 5, d = t & 31;
    wbf[t*256 + f] = rdbf(wg, h*8192 + f*32 + d, bf);   // Wcat[o=h*32+d][e]
  } else if (m <= 5) {
    int dst = m*65536 + t*256 + f;          // W[o=t][e=f]
    if (m == 1)      wbf[dst] = rdbf(lin_w, t*256 + f, bf);
    else if (m == 2) wbf[dst] = rdbf(inp_w, t*256 + f, bf);
    else if (m == 3) wbf[dst] = rdbf(inp_w, (256 + t)*256 + f, bf);
    else if (m == 4) wbf[dst] = rdbf(inp_w, (512 + t)*256 + f, bf);
    else             wbf[dst] = rdbf(out_w, t*256 + f, bf);
  } else if (m == 6) {
    if (f < 8)       ws[ST1_OFF + f*256 + t] = 0.0f;     // raw stat accs
    else if (f < 16) ws[ST2_OFF + (f - 8)*256 + t] = 0.0f;
    if (f == 0) {
      ws[BIAS_OFF + t]        = ldin(lin_b, t, bf);
      ws[BIAS_OFF + 256 + t]  = ldin(inp_b, t, bf);
      ws[BIAS_OFF + 512 + t]  = ldin(inp_b, 256 + t, bf);
      ws[BIAS_OFF + 768 + t]  = ldin(inp_b, 512 + t, bf);
      ws[BIAS_OFF + 1024 + t] = ldin(out_b, t, bf);
      ws[BIAS_OFF + 1280 + t] = ldin(a1, t, bf);
      ws[BIAS_OFF + 1536 + t] = ldin(a2, t, bf);
      ws[CS_OFF + 4096 + t]   = 0.0f;        // zero bias for Wcat GEMM
      if (t == 0) *flagp = bf;
    }
  } else {
    // m == 7: packadj, rows f*16 .. f*16+15
    unsigned long long* pkw = (unsigned long long*)(ws + PK_OFF);
    int w = t >> 6, lane = t & 63;
    for (int rr = 0; rr < 16; ++rr) {
      long row = (long)f*16 + rr;
      #pragma unroll
      for (int j = 0; j < 4; ++j) {
        int mm = t + 256*j;
        bool bit = adj[row*1024 + mm] > 0;
        unsigned long long msk = __ballot(bit);
        if (lane == 0) pkw[row*16 + w + 4*j] = msk;
      }
    }
  }
}

// ------- graph attention, head-split, 32 REAL rows/block -------------------
// GRID 1024, BLOCK 512 (8 waves): 4b x 32 groups x 8h; h in low 3 bits
// (XCD-L2 locality on WhT). adj from packed bitmask (scalar loads).
// Softmax register-resident: wave w owns rows 4w..4w+3. P bf16 in Pb[32]
// (two 16-row A-frag groups; PV shares each bw load across both groups).
// PV: wave w -> d-tile (w&1), key-chunks (w>>1)*8..+7; opart OVERLAYS the
// dead Pb/s2s arena after a barrier. LDS 68.5 KB -> 2 blocks/CU. Writes:
//   C region: raw xa slice  xa[b,n,h*32+d] = x + leaky(PV)
//   MX/RS: per-(h,row) softmax max and 1/sum (consumed by eout8)
#define PB_S 1032    // Pb row stride (ushorts); 2064 B -> m*4 banks, conflict-free
__global__ __launch_bounds__(512) void attn1a_kernel(const void* x, float* ws,
                                                     const int* flagp) {
  const int bf = *flagp;
  int t = threadIdx.x;
  int gid = blockIdx.x;
  int h = gid & 7;
  int b = (gid >> 3) & 3;
  int n0 = (gid >> 5) * 32;               // gid>>5 in 0..31
  __shared__ __align__(16) unsigned char arena[4096 + 32*PB_S*2];  // 68.5 KB
  float* s2s = (float*)arena;
  unsigned short (*Pb)[PB_S] = (unsigned short (*)[PB_S])(arena + 4096);
  float (*opart)[32][17] = (float (*)[32][17])arena;   // overlay (after Pb dead)
  int w = t >> 6, lane = t & 63;          // w 0..7
  int m = lane & 15, quad = lane >> 4;
  const unsigned long long* pk = (const unsigned long long*)(ws + PK_OFF);
  const float* s2p = ws + S2_OFF + h*4096 + b*1024;
  #pragma unroll
  for (int j = 0; j < 2; ++j) s2s[t + 512*j] = s2p[t + 512*j];
  __syncthreads();
  // ---- softmax rows n0+4w .. n0+4w+3, head h: register resident -----------
  #pragma unroll
  for (int rr = 0; rr < 4; ++rr) {
    int r = 4*w + rr;
    int rowi = __builtin_amdgcn_readfirstlane(b*1024 + n0 + r);
    const unsigned long long* prow = pk + (long)rowi * 16;   // wave-uniform
    float s1v = ws[S1_OFF + h*4096 + rowi];
    float p[16];
    float mx = -3.4e38f;
    #pragma unroll
    for (int j = 0; j < 16; ++j) {
      int mm = lane + 64*j;
      float ev = s1v + s2s[mm];
      ev = (ev >= 0.0f) ? ev : 0.1f*ev;
      ev = ((prow[j] >> lane) & 1ull) ? ev : NEGC;
      p[j] = ev;
      mx = fmaxf(mx, ev);
    }
    #pragma unroll
    for (int off = 32; off > 0; off >>= 1) mx = fmaxf(mx, __shfl_xor(mx, off));
    float s = 0.0f;
    #pragma unroll
    for (int j = 0; j < 16; ++j) { p[j] = __expf(p[j] - mx); s += p[j]; }
    #pragma unroll
    for (int off = 32; off > 0; off >>= 1) s += __shfl_xor(s, off);
    float rs = 1.0f / s;
    #pragma unroll
    for (int j = 0; j < 16; ++j)
      Pb[r][lane + 64*j] = f2bf(p[j] * rs);
    if (lane == 0) {
      ws[MX_OFF + h*4096 + rowi] = mx;
      ws[RS_OFF + h*4096 + rowi] = rs;
    }
  }
  __syncthreads();
  // ---- PV via MFMA: wave w -> d-tile (w&1), key-chunks (w>>1)*8 .. +7 -----
  f32x4 g0, g1;
  {
    const unsigned short* wht = (const unsigned short*)(ws + A_OFF);
    int ntile = w & 1;
    int ktbase = (w >> 1) * 8;
    int vd = ntile*16 + m;
    const unsigned short* wrow = wht + ((long)((b*8 + h)*32 + vd))*1024;
    f32x4 a0g0 = {0,0,0,0}, a1g0 = {0,0,0,0};
    f32x4 a0g1 = {0,0,0,0}, a1g1 = {0,0,0,0};
    #pragma unroll
    for (int kt2 = 0; kt2 < 4; ++kt2) {
      int kt = ktbase + 2*kt2;
      bf16x8s bw0 = *(const bf16x8s*)(wrow + kt*32 + quad*8);
      bf16x8s bw1 = *(const bf16x8s*)(wrow + (kt+1)*32 + quad*8);
      bf16x8s p00 = *(const bf16x8s*)&Pb[m][kt*32 + quad*8];
      bf16x8s p01 = *(const bf16x8s*)&Pb[16 + m][kt*32 + quad*8];
      a0g0 = __builtin_amdgcn_mfma_f32_16x16x32_bf16(p00, bw0, a0g0, 0, 0, 0);
      a0g1 = __builtin_amdgcn_mfma_f32_16x16x32_bf16(p01, bw0, a0g1, 0, 0, 0);
      bf16x8s p10 = *(const bf16x8s*)&Pb[m][(kt+1)*32 + quad*8];
      bf16x8s p11 = *(const bf16x8s*)&Pb[16 + m][(kt+1)*32 + quad*8];
      a1g0 = __builtin_amdgcn_mfma_f32_16x16x32_bf16(p10, bw1, a1g0, 0, 0, 0);
      a1g1 = __builtin_amdgcn_mfma_f32_16x16x32_bf16(p11, bw1, a1g1, 0, 0, 0);
    }
    g0 = a0g0 + a1g0;
    g1 = a0g1 + a1g1;
  }
  __syncthreads();          // all Pb reads complete -> arena reusable
  #pragma unroll
  for (int i = 0; i < 4; ++i) {
    opart[w][quad*4 + i][m]      = g0[i];
    opart[w][16 + quad*4 + i][m] = g1[i];
  }
  __syncthreads();
  #pragma unroll
  for (int half = 0; half < 2; ++half) {
    int r = (t >> 5) + half*16;         // 16 rows per half
    int dd = t & 31;
    int nt = dd >> 4, c = dd & 15;
    float sum = opart[nt][r][c] + opart[nt + 2][r][c]
              + opart[nt + 4][r][c] + opart[nt + 6][r][c];
    float hv = (sum >= 0.0f) ? sum : 0.01f*sum;
    long idx = (long)(b*1024 + n0 + r)*256 + h*32 + dd;
    ws[C_OFF + idx] = ldin(x, idx, bf) + hv;   // raw residual row slice
  }
}

// ---- eout8: rownorm(xa)->B + e_out + atomic column partials -> ST1 --------
// GRID 512, BLOCK 512 (8 waves): 8 rows/block, wave w owns row gid*8+w.
__global__ __launch_bounds__(512) void eout8_kernel(float* ws, void* dout,
                                                    const int* flagp) {
  const int bf = *flagp;
  int t = threadIdx.x;
  int gid = blockIdx.x;                // 0..511
  int b = gid >> 7;
  long r0 = (long)gid * 8;
  int w = t >> 6, lane = t & 63;
  __shared__ __align__(16) float s2s[8][1026];   // 32.8 KB
  __shared__ __align__(16) float Brow[8][260];   // 8.3 KB
  for (int i = t; i < 8192; i += 512) {
    int h = i >> 10, m = i & 1023;
    s2s[h][m] = ws[S2_OFF + h*4096 + b*1024 + m];
  }
  // ---- rownorm (ddof=1) of raw xa row r0+w, wave-local --------------------
  long row = r0 + w;
  float vals[4];
  float s = 0.0f;
  #pragma unroll
  for (int j = 0; j < 4; ++j) {
    vals[j] = ws[C_OFF + row*256 + lane + 64*j];
    s += vals[j];
  }
  #pragma unroll
  for (int off = 32; off > 0; off >>= 1) s += __shfl_xor(s, off);
  float mean = s * (1.0f/256.0f);
  float ss = 0.0f;
  #pragma unroll
  for (int j = 0; j < 4; ++j) { float d = vals[j] - mean; ss += d*d; }
  #pragma unroll
  for (int off = 32; off > 0; off >>= 1) ss += __shfl_xor(ss, off);
  float inv = 1.0f / (sqrtf(ss * (1.0f/255.0f)) + 1e-6f);
  #pragma unroll
  for (int j = 0; j < 4; ++j) {
    float nv = (vals[j] - mean) * inv;
    ws[B_OFF + row*256 + lane + 64*j] = nv;
    Brow[w][lane + 64*j] = nv;
  }
  __syncthreads();          // s2s staged + Brow complete
  // ---- e_out for row r0+w --------------------------------------------------
  const unsigned long long* prow =
      (const unsigned long long*)(ws + PK_OFF) + row*16;
  float s1v[8], mxv[8], rsv[8];
  #pragma unroll
  for (int h = 0; h < 8; ++h) {
    s1v[h] = ws[S1_OFF + h*4096 + row];
    mxv[h] = ws[MX_OFF + h*4096 + row];
    rsv[h] = ws[RS_OFF + h*4096 + row];
  }
  #pragma unroll
  for (int j = 0; j < 16; ++j) {
    int m = lane + 64*j;
    bool a = (prow[j] >> lane) & 1ull;
    float acc = 0.0f;
    #pragma unroll
    for (int h = 0; h < 8; ++h) {
      float ev = s1v[h] + s2s[h][m];
      ev = (ev >= 0.0f) ? ev : 0.1f*ev;
      ev = a ? ev : NEGC;
      acc += rsv[h] * __expf(ev - mxv[h]);
    }
    stout(dout, 1048576L + row*1024 + m, 0.125f*acc, bf);
  }
  // ---- column partials -> raw ST1 accumulators ----------------------------
  if (t < 256) {
    float ps = 0, pss = 0;
    #pragma unroll
    for (int r = 0; r < 8; ++r) { float v = Brow[r][t]; ps += v; pss += v*v; }
    atomicAdd(&ws[ST1_OFF + b*256 + t], ps);
    atomicAdd(&ws[ST1_OFF + 1024 + b*256 + t], pss);
  }
}

// ---------------- MFMA row-GEMM, fp32-accurate via bf16 hi/lo split --------
// out[row][o] = sum_e in[row][e] * W[o][e] + bias[o];  in = hi + lo (bf16).
// Block 512 thr (8 waves), 16 rows staged in LDS (bf16 hi/lo, pad 264).
// CS=2: grid 512 = 256 rowgroups x 2 colhalves. CS=1: grid 256 (RN-able).
// IN_MODE 0: d_in flat; 1: fp32 + colnorm from RAW sums/sumsq in st
//   (mean/inv computed inline); 2: src permuted; 3: fp32 head-major.
// OUTM 0 fp32 flat (RN=1: fused rownorm + atomic raw ST2 partials -> csout);
//   1: d_out; 4: bf16 T hm; 5: DUAL Q/K.  SOP=1: s1/s2 head reductions.
template<int IN_MODE, int RN, int OUTM, int CS, int SOP>
__global__ __launch_bounds__(512) void gemm2_kernel(const void* inp,
    const unsigned short* wmat, const unsigned short* wmat2,
    const float* bias, const float* bias2, const float* st,
    void* outp, float* csout, const int* flagp) {
  const int bf = *flagp;
  int t = threadIdx.x;
  int gid = blockIdx.x;
  int rowg = (CS == 2) ? (gid >> 1) : gid;
  int colbase = (CS == 2) ? ((gid & 1) * 128) : 0;
  int r0 = rowg * 16;
  __shared__ __align__(16) unsigned short Usm[2*16*264];    // 16.9 KB
  unsigned short (*Uh)[264] = (unsigned short (*)[264])Usm;
  unsigned short (*Ul)[264] = (unsigned short (*)[264])(Usm + 16*264);
  // ---- stage 16 rows as bf16 hi/lo ----------------------------------------
  {
    int srow = t >> 5;
    int e0 = (t & 31) * 8;
    long grow = r0 + srow;
    float v[8];
    if (IN_MODE == 0) {
      #pragma unroll
      for (int j = 0; j < 8; ++j) v[j] = ldin(inp, grow*256 + e0 + j, bf);
    } else if (IN_MODE == 1) {
      int b = (int)(grow >> 10);
      const float* ip = (const float*)inp + grow*256 + e0;
      const float* sp_ = st + b*256 + e0;
      const float* qp_ = st + 1024 + b*256 + e0;
      #pragma unroll
      for (int j = 0; j < 8; ++j) {
        float sm = sp_[j], sq = qp_[j];
        float mean = sm * (1.0f/1024.0f);
        float var = fmaxf((sq - sm*mean) * (1.0f/1023.0f), 0.0f);
        float inv = 1.0f / (sqrtf(var) + 1e-6f);
        v[j] = (ip[j] - mean) * inv;
      }
    } else if (IN_MODE == 2) {
      int b = (int)(grow >> 10), n = (int)(grow & 1023);
      #pragma unroll
      for (int j = 0; j < 8; ++j)
        v[j] = ldin(inp, (long)(n*4 + b)*256 + e0 + j, bf);
    } else {
      int b = (int)(grow >> 10), n = (int)(grow & 1023);
      const float* ip = (const float*)inp
          + ((long)(b*8 + (e0 >> 5))*1024 + n)*32 + (e0 & 31);
      #pragma unroll
      for (int j = 0; j < 8; ++j) v[j] = ip[j];
    }
    unsigned short hv[8], lv[8];
    #pragma unroll
    for (int j = 0; j < 8; ++j) {
      hv[j] = f2bf(v[j]);
      lv[j] = f2bf(v[j] - bf2f(hv[j]));
    }
    *(bf16x8s*)&Uh[srow][e0] = *(bf16x8s*)hv;
    *(bf16x8s*)&Ul[srow][e0] = *(bf16x8s*)lv;
  }
  __syncthreads();
  int w = t >> 6, lane = t & 63, m = lane & 15, quad = lane >> 4;
  const int NT = (CS == 1) ? 2 : 1;
  f32x4 accs[2];
  f32x4 acck;
  #pragma unroll
  for (int nt = 0; nt < NT; ++nt) {
    int o = colbase + w*16 + nt*128 + m;
    const unsigned short* wp = wmat + o*256 + quad*8;
    f32x4 ah_acc = {0,0,0,0}, al_acc = {0,0,0,0};
    f32x4 kh_acc = {0,0,0,0}, kl_acc = {0,0,0,0};
    const unsigned short* wp2 = (OUTM == 5) ? (wmat2 + o*256 + quad*8) : wp;
    #pragma unroll
    for (int kt = 0; kt < 8; ++kt) {
      bf16x8s ah = *(const bf16x8s*)&Uh[m][kt*32 + quad*8];
      bf16x8s al = *(const bf16x8s*)&Ul[m][kt*32 + quad*8];
      bf16x8s bw = *(const bf16x8s*)(wp + kt*32);
      ah_acc = __builtin_amdgcn_mfma_f32_16x16x32_bf16(ah, bw, ah_acc, 0, 0, 0);
      al_acc = __builtin_amdgcn_mfma_f32_16x16x32_bf16(al, bw, al_acc, 0, 0, 0);
      if (OUTM == 5) {
        bf16x8s bw2 = *(const bf16x8s*)(wp2 + kt*32);
        kh_acc = __builtin_amdgcn_mfma_f32_16x16x32_bf16(ah, bw2, kh_acc, 0, 0, 0);
        kl_acc = __builtin_amdgcn_mfma_f32_16x16x32_bf16(al, bw2, kl_acc, 0, 0, 0);
      }
    }
    accs[nt] = ah_acc + al_acc;
    if (OUTM == 5) acck = kh_acc + kl_acc;
    if (RN == 0) {
      float bv = bias[o];
      if constexpr (OUTM == 0) {
        #pragma unroll
        for (int i = 0; i < 4; ++i) {
          long row = r0 + quad*4 + i;
          ((float*)outp)[row*256 + o] = accs[nt][i] + bv;
        }
      } else if constexpr (OUTM == 1) {
        #pragma unroll
        for (int i = 0; i < 4; ++i) {
          long row = r0 + quad*4 + i;
          stout(outp, row*256 + o, accs[nt][i] + bv, bf);
        }
      } else if constexpr (OUTM == 4) {
        int h = o >> 5, d = o & 31;
        #pragma unroll
        for (int i = 0; i < 4; ++i) {
          long row = r0 + quad*4 + i;
          int b = (int)(row >> 10), n = (int)(row & 1023);
          ((unsigned short*)outp)[((long)((b*8 + h)*32 + d))*1024 + n]
              = f2bf(accs[nt][i] + bv);
        }
      } else if constexpr (OUTM == 5) {
        float* wsf = (float*)outp;                 // outp = ws base
        float* qhm = wsf + A_OFF;
        unsigned short* khm = (unsigned short*)(wsf + B_OFF);
        float bq = bias[o], bk = bias2[o];
        int h = o >> 5, d = o & 31;
        #pragma unroll
        for (int i = 0; i < 4; ++i) {
          long row = r0 + quad*4 + i;
          int b = (int)(row >> 10), n = (int)(row & 1023);
          long idx = ((long)((b*8 + h)*1024 + n))*32 + d;
          qhm[idx] = accs[nt][i] + bq;
          khm[idx] = f2bf(acck[i] + bk);
        }
      }
    }
  }
  if constexpr (SOP == 1) {
    // s1/s2 head reductions from the Wh accumulators (CS=2 -> NT=1).
    __shared__ float sp[2][8][16];
    int o = colbase + w*16 + m;
    float a1v = bias2[o];
    float a2v = st[o];
    #pragma unroll
    for (int i = 0; i < 4; ++i) {
      float v1 = accs[0][i] * a1v;
      float v2 = accs[0][i] * a2v;
      #pragma unroll
      for (int off = 8; off > 0; off >>= 1) {
        v1 += __shfl_xor(v1, off);
        v2 += __shfl_xor(v2, off);
      }
      if (m == 0) {
        sp[0][w][quad*4 + i] = v1;
        sp[1][w][quad*4 + i] = v2;
      }
    }
    __syncthreads();
    if (t < 128) {
      int which = t >> 6, h2 = (t >> 4) & 3, r = t & 15;
      float v = sp[which][2*h2][r] + sp[which][2*h2 + 1][r];
      long dst = (which ? S2_OFF : S1_OFF)
               + (long)((colbase >> 5) + h2)*4096 + (r0 + r);
      csout[dst] = v;
    }
  }
  if constexpr (RN == 1) {
    // overlay O (fp32 16x264) on Usm; all U reads are done
    __syncthreads();
    float (*O)[264] = (float (*)[264])Usm;
    #pragma unroll
    for (int nt = 0; nt < NT; ++nt) {
      int oc = colbase + w*16 + nt*128 + m;
      float bv = bias[oc];
      #pragma unroll
      for (int i = 0; i < 4; ++i)
        O[quad*4 + i][oc] = accs[nt][i] + bv;
    }
    __syncthreads();
    #pragma unroll
    for (int rr = 0; rr < 2; ++rr) {
      int r = 2*w + rr;
      float vals[4]; float s = 0.0f;
      #pragma unroll
      for (int j = 0; j < 4; ++j) { vals[j] = O[r][lane + 64*j]; s += vals[j]; }
      #pragma unroll
      for (int off = 32; off > 0; off >>= 1) s += __shfl_xor(s, off);
      float mean = s * (1.0f/256.0f);
      float ss = 0.0f;
      #pragma unroll
      for (int j = 0; j < 4; ++j) { float d = vals[j] - mean; ss += d*d; }
      #pragma unroll
      for (int off = 32; off > 0; off >>= 1) ss += __shfl_xor(ss, off);
      float inv = 1.0f / (sqrtf(ss * (1.0f/255.0f)) + 1e-6f);
      #pragma unroll
      for (int j = 0; j < 4; ++j) {
        float nv = (vals[j] - mean) * inv;
        ((float*)outp)[(long)(r0 + r)*256 + lane + 64*j] = nv;
        O[r][lane + 64*j] = nv;      // write back for column partials
      }
    }
    __syncthreads();
    if (csout != nullptr && t < 256) {
      int b = r0 >> 10;
      float s = 0, ss = 0;
      #pragma unroll
      for (int r = 0; r < 16; ++r) { float v = O[r][t]; s += v; ss += v*v; }
      atomicAdd(&csout[b*256 + t], s);          // raw ST2 sums
      atomicAdd(&csout[1024 + b*256 + t], ss);
    }
  }
}

// -------- MHA via MFMA, flash-register softmax, 32 REAL q-rows/block -------
// GRID 1024, BLOCK 512 (8 waves): 32 row-groups x 4 b x 8 h (h low 3 bits).
// Q fp32 hm [b][h][n][32] at A_OFF (o overwrites q, exclusive slots);
// K bf16 [b][h][n][32] at B_OFF; V^T bf16 [b][h][d][n] at C_OFF.
// Two 16-row A-frag groups share every K/V B-operand load (QK and PV):
// per-row MFMA unchanged, K/V L2 traffic and per-block fixed cost HALVED
// vs the 16-row version. QK output stays in registers (s0/s1g [8][4]);
// per-wave partial max/sum per group + 32-thread combine; waves write
// normalized bf16 P directly. PV accumulates in regs -> barrier -> opart
// OVERLAYS the dead P arena. LDS 68.7 KB -> 2 blocks/CU.
#define P2S 1036
__global__ __launch_bounds__(512) void attn2_kernel(float* ws) {
  int t = threadIdx.x;
  int gid = blockIdx.x;
  int h = gid & 7;
  int b = (gid >> 3) & 3;
  int n0 = (gid >> 5) << 5;   // 32 q-rows per block; gid>>5 in 0..31
  __shared__ __align__(16) unsigned short P[32][P2S];   // 66.3 KB
  __shared__ float pmx[8][32];
  __shared__ float psm[8][32];
  __shared__ float gmx[32];
  __shared__ float grs[32];
  float (*opart)[32][17] = (float (*)[32][17])P;   // overlay (after P dead)
  float* qq = ws + A_OFF;
  const unsigned short* kk = (const unsigned short*)(ws + B_OFF);
  const unsigned short* vt = (const unsigned short*)(ws + C_OFF);
  int base_bh = (b*8 + h)*1024;
  int w = t >> 6, lane = t & 63;   // w 0..7
  int m = lane & 15, quad = lane >> 4;
  const float scl = 0.17677669529663687f; // 1/sqrt(32)
  float s0[8][4], s1g[8][4];
  // ---- QK via MFMA into registers: wave w covers keys w*128 .. +127 -------
  {
    const float* qp0 = qq + (base_bh + n0 + m)*32 + quad*8;
    const float* qp1 = qq + (base_bh + n0 + 16 + m)*32 + quad*8;
    bf16x8s aq0, aq1;
    #pragma unroll
    for (int j = 0; j < 8; ++j) {
      ((unsigned short*)&aq0)[j] = f2bf(qp0[j]);
      ((unsigned short*)&aq1)[j] = f2bf(qp1[j]);
    }
    f32x4 zero = {0.0f, 0.0f, 0.0f, 0.0f};
    #pragma unroll
    for (int kt = 0; kt < 8; ++kt) {
      int kbase = w*128 + kt*16;
      bf16x8s bk = *(const bf16x8s*)(kk + (base_bh + kbase + m)*32 + quad*8);
      f32x4 d0 = __builtin_amdgcn_mfma_f32_16x16x32_bf16(aq0, bk, zero, 0, 0, 0);
      f32x4 d1 = __builtin_amdgcn_mfma_f32_16x16x32_bf16(aq1, bk, zero, 0, 0, 0);
      #pragma unroll
      for (int i = 0; i < 4; ++i) { s0[kt][i] = d0[i] * scl; s1g[kt][i] = d1[i] * scl; }
    }
  }
  // ---- per-wave partial max/sum (both groups) -----------------------------
  #pragma unroll
  for (int g = 0; g < 2; ++g) {
    #pragma unroll
    for (int i = 0; i < 4; ++i) {
      float mx = (g ? s1g[0][i] : s0[0][i]);
      #pragma unroll
      for (int kt = 1; kt < 8; ++kt) mx = fmaxf(mx, (g ? s1g[kt][i] : s0[kt][i]));
      #pragma unroll
      for (int off = 8; off > 0; off >>= 1) mx = fmaxf(mx, __shfl_xor(mx, off));
      float sm = 0.0f;
      #pragma unroll
      for (int kt = 0; kt < 8; ++kt) sm += __expf((g ? s1g[kt][i] : s0[kt][i]) - mx);
      #pragma unroll
      for (int off = 8; off > 0; off >>= 1) sm += __shfl_xor(sm, off);
      if (m == 0) {
        pmx[w][g*16 + quad*4 + i] = mx;
        psm[w][g*16 + quad*4 + i] = sm;
      }
    }
  }
  __syncthreads();
  if (t < 32) {
    float mx = pmx[0][t];
    #pragma unroll
    for (int w2 = 1; w2 < 8; ++w2) mx = fmaxf(mx, pmx[w2][t]);
    float den = 0.0f;
    #pragma unroll
    for (int w2 = 0; w2 < 8; ++w2) den += psm[w2][t] * __expf(pmx[w2][t] - mx);
    gmx[t] = mx;
    grs[t] = 1.0f / den;
  }
  __syncthreads();
  // ---- write normalized P bf16 (both groups) ------------------------------
  #pragma unroll
  for (int g = 0; g < 2; ++g) {
    #pragma unroll
    for (int i = 0; i < 4; ++i) {
      int row = g*16 + quad*4 + i;
      float mx = gmx[row], rs = grs[row];
      #pragma unroll
      for (int kt = 0; kt < 8; ++kt)
        P[row][w*128 + kt*16 + m] =
            f2bf(__expf((g ? s1g[kt][i] : s0[kt][i]) - mx) * rs);
    }
  }
  __syncthreads();
  // ---- PV via MFMA: wave w -> d-tile (w&1), key-chunks (w>>1)*8 .. +7 -----
  f32x4 g0, g1;
  {
    int ntile = w & 1;
    int ktbase = (w >> 1) * 8;
    int vd = ntile*16 + m;
    const unsigned short* vrow = vt + base_bh*32 + vd*1024;
    const unsigned short* P0 = &P[m][0];
    const unsigned short* P1 = &P[16 + m][0];
    f32x4 a0g0 = {0,0,0,0}, a1g0 = {0,0,0,0};
    f32x4 a0g1 = {0,0,0,0}, a1g1 = {0,0,0,0};
    #pragma unroll
    for (int kt2 = 0; kt2 < 4; ++kt2) {
      int kt = ktbase + 2*kt2;
      bf16x8s bv0 = *(const bf16x8s*)(vrow + kt*32 + quad*8);
      bf16x8s bv1 = *(const bf16x8s*)(vrow + (kt+1)*32 + quad*8);
      bf16x8s p00 = *(const bf16x8s*)(P0 + kt*32 + quad*8);
      bf16x8s p01 = *(const bf16x8s*)(P1 + kt*32 + quad*8);
      a0g0 = __builtin_amdgcn_mfma_f32_16x16x32_bf16(p00, bv0, a0g0, 0, 0, 0);
      a0g1 = __builtin_amdgcn_mfma_f32_16x16x32_bf16(p01, bv0, a0g1, 0, 0, 0);
      bf16x8s p10 = *(const bf16x8s*)(P0 + (kt+1)*32 + quad*8);
      bf16x8s p11 = *(const bf16x8s*)(P1 + (kt+1)*32 + quad*8);
      a1g0 = __builtin_amdgcn_mfma_f32_16x16x32_bf16(p10, bv1, a1g0, 0, 0, 0);
      a1g1 = __builtin_amdgcn_mfma_f32_16x16x32_bf16(p11, bv1, a1g1, 0, 0, 0);
    }
    g0 = a0g0 + a1g0;
    g1 = a0g1 + a1g1;
  }
  __syncthreads();          // all P reads complete -> arena reusable
  #pragma unroll
  for (int i = 0; i < 4; ++i) {
    opart[w][quad*4 + i][m]      = g0[i];
    opart[w][16 + quad*4 + i][m] = g1[i];
  }
  __syncthreads();
  #pragma unroll
  for (int half = 0; half < 2; ++half) {
    int r = (t >> 5) + half*16;         // 16 rows per half
    int d = t & 31;
    int nt = d >> 4, c = d & 15;
    float sum = opart[nt][r][c] + opart[nt + 2][r][c]
              + opart[nt + 4][r][c] + opart[nt + 6][r][c];
    qq[(base_bh + n0 + r)*32 + d] = sum;   // o over q (own slots)
  }
}

extern "C" void kernel_launch(void* const* d_in, const int* in_sizes, int n_in,
                              void* d_out, int out_size, void* d_ws, size_t ws_size,
                              hipStream_t stream) {
  const void* x   = d_in[0];
  const void* src = d_in[1];
  const int* adj  = (const int*)d_in[2];
  const void* wg  = d_in[3];
  const void* a1  = d_in[4];
  const void* a2  = d_in[5];
  const void* lw  = d_in[6];
  const void* lb  = d_in[7];
  const void* ipw = d_in[8];
  const void* ipb = d_in[9];
  const void* opw = d_in[10];
  const void* opb = d_in[11];
  float* ws = (float*)d_ws;
  const unsigned short* wbf = (const unsigned short*)d_ws;
  int* flagp = (int*)(ws + FLAG_F);

  setup_kernel<<<dim3(256, 8), 256, 0, stream>>>(x, wg, lw, ipw, opw, lb, ipb,
      opb, a1, a2, adj, ws, flagp);                        // weights+bias+adj+zero
  gemm2_kernel<0,0,4,2,1><<<512, 512, 0, stream>>>(x, wbf + 0*65536,
      nullptr, ws + CS_OFF + 4096, ws + BIAS_OFF + 1280, ws + BIAS_OFF + 1536,
      ws + A_OFF, ws, flagp);                              // WhT -> A; s1/s2
  attn1a_kernel<<<1024, 512, 0, stream>>>(x, ws, flagp);   // xa -> C, mx/rs
  eout8_kernel<<<512, 512, 0, stream>>>(ws, d_out, flagp); // e_out; rownorm -> B; ST1
  gemm2_kernel<1,1,0,1,0><<<256, 512, 0, stream>>>(ws + B_OFF, wbf + 1*65536,
      nullptr, ws + BIAS_OFF, nullptr, ws + ST1_OFF, ws + C_OFF, ws + ST2_OFF,
      flagp);                                              // lin+RN -> C; ST2
  gemm2_kernel<1,0,5,2,0><<<512, 512, 0, stream>>>(ws + C_OFF, wbf + 2*65536,
      wbf + 3*65536, ws + BIAS_OFF + 256, ws + BIAS_OFF + 512, ws + ST2_OFF,
      ws, nullptr, flagp);                                 // Q -> A, K -> B
  gemm2_kernel<2,0,4,2,0><<<512, 512, 0, stream>>>(src, wbf + 4*65536,
      nullptr, ws + BIAS_OFF + 768, nullptr, nullptr, ws + C_OFF, nullptr,
      flagp);                                              // V^T -> C
  attn2_kernel<<<1024, 512, 0, stream>>>(ws);              // o -> A_OFF
  gemm2_kernel<3,0,1,2,0><<<512, 512, 0, stream>>>(ws + A_OFF, wbf + 5*65536,
      nullptr, ws + BIAS_OFF + 1024, nullptr, nullptr, d_out, nullptr,
      flagp);                                              // out-proj
}

// Round 12
// 243.061 us; speedup vs baseline: 1.0114x; 1.0114x over previous
//
#include <hip/hip_runtime.h>
#include <hip/hip_bf16.h>

// B=4, N=1024, E=256, H=8, D=32. Float tensors may be bf16 OR fp32 in d_in /
// d_out (detected at runtime on-device); adj is int32.
// Output: x_out [4,1024,256] then e_out [4,1024,1024] (element offsets).
//
// ws float offsets:
//   [0 .. 196608)   : weight matrices, bf16, ushort offset m*65536, ALL o-major
//       W[o][e] at m*65536 + o*256 + e.  m: 0=Wcat 1=LIN 2=WQ 3=WK 4=WV 5=WO
#define BIAS_OFF 196608   // lin_b, bq, bk, bv, bo, a1, a2  (7*256 fp32)
#define S1_OFF   198400   // [h][4096]
#define S2_OFF   231168
#define CS_OFF   263936   // +4096: zero-bias[256] (setup-filled)
#define ST1_OFF  296704   // RAW col stats xa-norm: sum[4][256] + sumsq[4][256] (atomic)
#define ST2_OFF  298752   // RAW col stats lin-norm: sum + sumsq (atomic)
#define A_OFF    300800   // WhT bf16 [b][h][d][n] (2 MB) -> later Q,o fp32 head-major
#define MX_OFF   825088   // softmax row max [h][4096] (dead before Q overlays)
#define RS_OFF   857856   // softmax row 1/sum [h][4096]
#define PK_OFF   890624   // packed adj bitmask: [4096 rows][16 u64] (dead after eout8)
#define B_OFF    1349376  // 4 MB: rownorm(xa)     -> later K bf16 head-major [b][h][n][32]
#define C_OFF    2397952  // 4 MB: raw xa, then rownorm(lin) -> later V^T bf16 hm [b][h][d][n]
#define FLAG_F   3446528  // int: 1 = bf16 tensors, 0 = fp32 tensors
// end 3446529 floats = 13.8 MB

#define NEGC (-9.0e15f)

typedef __attribute__((ext_vector_type(8))) short bf16x8s;
typedef __attribute__((ext_vector_type(4))) float f32x4;

static __device__ __forceinline__ float bf2f(unsigned short u) {
  union { unsigned int i; float f; } v; v.i = ((unsigned int)u) << 16; return v.f;
}
static __device__ __forceinline__ unsigned short f2bf(float f) {
  union { float f; unsigned int u; } v; v.f = f;
  unsigned int r = (v.u + 0x7FFFu + ((v.u >> 16) & 1u)) >> 16;   // RNE
  return (unsigned short)r;
}
static __device__ __forceinline__ float ldin(const void* p, long i, int bf) {
  return bf ? bf2f(((const unsigned short*)p)[i]) : ((const float*)p)[i];
}
static __device__ __forceinline__ unsigned short rdbf(const void* p, long i, int bf) {
  if (bf) return ((const unsigned short*)p)[i];
  return f2bf(((const float*)p)[i]);
}
static __device__ __forceinline__ void stout(void* p, long i, float v, int bf) {
  if (bf) ((unsigned short*)p)[i] = f2bf(v);
  else    ((float*)p)[i] = v;
}

// ------- setup: detect(local) + weights o-major + biases + packadj + zero --
// Grid dim3(256, 8), block 256. Each block derives the dtype flag locally
// (wave-0 ballot on x) -- no cross-kernel dependency. m=0..5 weights,
// m=6: biases/zero-accs/flag-write, m=7: packadj 16 rows per block.
__global__ __launch_bounds__(256) void setup_kernel(
    const void* x, const void* wg, const void* lin_w, const void* inp_w,
    const void* out_w, const void* lin_b, const void* inp_b, const void* out_b,
    const void* a1, const void* a2, const int* adj, float* ws, int* flagp) {
  int t = threadIdx.x;
  int f = blockIdx.x;
  int m = blockIdx.y;
  __shared__ int bfs;
  if (t < 64) {
    unsigned short u = ((const unsigned short*)x)[2 * t];
    int e = (u >> 7) & 0xFF;
    bool good = (e >= 100 && e <= 140);
    unsigned long long msk = __ballot(good);
    if (t == 0) bfs = (__popcll(msk) >= 48) ? 1 : 0;
  }
  __syncthreads();
  const int bf = bfs;
  unsigned short* wbf = (unsigned short*)ws;
  if (m == 0) {
    int h = t >> 5, d = t & 31;
    wbf[t*256 + f] = rdbf(wg, h*8192 + f*32 + d, bf);   // Wcat[o=h*32+d][e]
  } else if (m <= 5) {
    int dst = m*65536 + t*256 + f;          // W[o=t][e=f]
    if (m == 1)      wbf[dst] = rdbf(lin_w, t*256 + f, bf);
    else if (m == 2) wbf[dst] = rdbf(inp_w, t*256 + f, bf);
    else if (m == 3) wbf[dst] = rdbf(inp_w, (256 + t)*256 + f, bf);
    else if (m == 4) wbf[dst] = rdbf(inp_w, (512 + t)*256 + f, bf);
    else             wbf[dst] = rdbf(out_w, t*256 + f, bf);
  } else if (m == 6) {
    if (f < 8)       ws[ST1_OFF + f*256 + t] = 0.0f;     // raw stat accs
    else if (f < 16) ws[ST2_OFF + (f - 8)*256 + t] = 0.0f;
    if (f == 0) {
      ws[BIAS_OFF + t]        = ldin(lin_b, t, bf);
      ws[BIAS_OFF + 256 + t]  = ldin(inp_b, t, bf);
      ws[BIAS_OFF + 512 + t]  = ldin(inp_b, 256 + t, bf);
      ws[BIAS_OFF + 768 + t]  = ldin(inp_b, 512 + t, bf);
      ws[BIAS_OFF + 1024 + t] = ldin(out_b, t, bf);
      ws[BIAS_OFF + 1280 + t] = ldin(a1, t, bf);
      ws[BIAS_OFF + 1536 + t] = ldin(a2, t, bf);
      ws[CS_OFF + 4096 + t]   = 0.0f;        // zero bias for Wcat GEMM
      if (t == 0) *flagp = bf;
    }
  } else {
    // m == 7: packadj, rows f*16 .. f*16+15
    unsigned long long* pkw = (unsigned long long*)(ws + PK_OFF);
    int w = t >> 6, lane = t & 63;
    for (int rr = 0; rr < 16; ++rr) {
      long row = (long)f*16 + rr;
      #pragma unroll
      for (int j = 0; j < 4; ++j) {
        int mm = t + 256*j;
        bool bit = adj[row*1024 + mm] > 0;
        unsigned long long msk = __ballot(bit);
        if (lane == 0) pkw[row*16 + w + 4*j] = msk;
      }
    }
  }
}

// ------- graph attention, head-split, 32 REAL rows/block -------------------
// GRID 1024, BLOCK 512 (8 waves): 4b x 32 groups x 8h; h in low 3 bits
// (XCD-L2 locality on WhT). adj from packed bitmask (scalar loads).
// Softmax register-resident: wave w owns rows 4w..4w+3. P bf16 in Pb[32]
// (two 16-row A-frag groups; PV shares each bw load across both groups).
// PV: wave w -> d-tile (w&1), key-chunks (w>>1)*8..+7; opart OVERLAYS the
// dead Pb/s2s arena after a barrier. LDS 68.5 KB -> 2 blocks/CU. Writes:
//   C region: raw xa slice  xa[b,n,h*32+d] = x + leaky(PV)
//   MX/RS: per-(h,row) softmax max and 1/sum (consumed by eout8)
#define PB_S 1032    // Pb row stride (ushorts); 2064 B -> m*4 banks, conflict-free
__global__ __launch_bounds__(512) void attn1a_kernel(const void* x, float* ws,
                                                     const int* flagp) {
  const int bf = *flagp;
  int t = threadIdx.x;
  int gid = blockIdx.x;
  int h = gid & 7;
  int b = (gid >> 3) & 3;
  int n0 = (gid >> 5) * 32;               // gid>>5 in 0..31
  __shared__ __align__(16) unsigned char arena[4096 + 32*PB_S*2];  // 68.5 KB
  float* s2s = (float*)arena;
  unsigned short (*Pb)[PB_S] = (unsigned short (*)[PB_S])(arena + 4096);
  float (*opart)[32][17] = (float (*)[32][17])arena;   // overlay (after Pb dead)
  int w = t >> 6, lane = t & 63;          // w 0..7
  int m = lane & 15, quad = lane >> 4;
  const unsigned long long* pk = (const unsigned long long*)(ws + PK_OFF);
  const float* s2p = ws + S2_OFF + h*4096 + b*1024;
  #pragma unroll
  for (int j = 0; j < 2; ++j) s2s[t + 512*j] = s2p[t + 512*j];
  __syncthreads();
  // ---- softmax rows n0+4w .. n0+4w+3, head h: register resident -----------
  #pragma unroll
  for (int rr = 0; rr < 4; ++rr) {
    int r = 4*w + rr;
    int rowi = __builtin_amdgcn_readfirstlane(b*1024 + n0 + r);
    const unsigned long long* prow = pk + (long)rowi * 16;   // wave-uniform
    float s1v = ws[S1_OFF + h*4096 + rowi];
    float p[16];
    float mx = -3.4e38f;
    #pragma unroll
    for (int j = 0; j < 16; ++j) {
      int mm = lane + 64*j;
      float ev = s1v + s2s[mm];
      ev = (ev >= 0.0f) ? ev : 0.1f*ev;
      ev = ((prow[j] >> lane) & 1ull) ? ev : NEGC;
      p[j] = ev;
      mx = fmaxf(mx, ev);
    }
    #pragma unroll
    for (int off = 32; off > 0; off >>= 1) mx = fmaxf(mx, __shfl_xor(mx, off));
    float s = 0.0f;
    #pragma unroll
    for (int j = 0; j < 16; ++j) { p[j] = __expf(p[j] - mx); s += p[j]; }
    #pragma unroll
    for (int off = 32; off > 0; off >>= 1) s += __shfl_xor(s, off);
    float rs = 1.0f / s;
    #pragma unroll
    for (int j = 0; j < 16; ++j)
      Pb[r][lane + 64*j] = f2bf(p[j] * rs);
    if (lane == 0) {
      ws[MX_OFF + h*4096 + rowi] = mx;
      ws[RS_OFF + h*4096 + rowi] = rs;
    }
  }
  __syncthreads();
  // ---- PV via MFMA: wave w -> d-tile (w&1), key-chunks (w>>1)*8 .. +7 -----
  f32x4 g0, g1;
  {
    const unsigned short* wht = (const unsigned short*)(ws + A_OFF);
    int ntile = w & 1;
    int ktbase = (w >> 1) * 8;
    int vd = ntile*16 + m;
    const unsigned short* wrow = wht + ((long)((b*8 + h)*32 + vd))*1024;
    f32x4 a0g0 = {0,0,0,0}, a1g0 = {0,0,0,0};
    f32x4 a0g1 = {0,0,0,0}, a1g1 = {0,0,0,0};
    #pragma unroll
    for (int kt2 = 0; kt2 < 4; ++kt2) {
      int kt = ktbase + 2*kt2;
      bf16x8s bw0 = *(const bf16x8s*)(wrow + kt*32 + quad*8);
      bf16x8s bw1 = *(const bf16x8s*)(wrow + (kt+1)*32 + quad*8);
      bf16x8s p00 = *(const bf16x8s*)&Pb[m][kt*32 + quad*8];
      bf16x8s p01 = *(const bf16x8s*)&Pb[16 + m][kt*32 + quad*8];
      a0g0 = __builtin_amdgcn_mfma_f32_16x16x32_bf16(p00, bw0, a0g0, 0, 0, 0);
      a0g1 = __builtin_amdgcn_mfma_f32_16x16x32_bf16(p01, bw0, a0g1, 0, 0, 0);
      bf16x8s p10 = *(const bf16x8s*)&Pb[m][(kt+1)*32 + quad*8];
      bf16x8s p11 = *(const bf16x8s*)&Pb[16 + m][(kt+1)*32 + quad*8];
      a1g0 = __builtin_amdgcn_mfma_f32_16x16x32_bf16(p10, bw1, a1g0, 0, 0, 0);
      a1g1 = __builtin_amdgcn_mfma_f32_16x16x32_bf16(p11, bw1, a1g1, 0, 0, 0);
    }
    g0 = a0g0 + a1g0;
    g1 = a0g1 + a1g1;
  }
  __syncthreads();          // all Pb reads complete -> arena reusable
  #pragma unroll
  for (int i = 0; i < 4; ++i) {
    opart[w][quad*4 + i][m]      = g0[i];
    opart[w][16 + quad*4 + i][m] = g1[i];
  }
  __syncthreads();
  #pragma unroll
  for (int half = 0; half < 2; ++half) {
    int r = (t >> 5) + half*16;         // 16 rows per half
    int dd = t & 31;
    int nt = dd >> 4, c = dd & 15;
    float sum = opart[nt][r][c] + opart[nt + 2][r][c]
              + opart[nt + 4][r][c] + opart[nt + 6][r][c];
    float hv = (sum >= 0.0f) ? sum : 0.01f*sum;
    long idx = (long)(b*1024 + n0 + r)*256 + h*32 + dd;
    ws[C_OFF + idx] = ldin(x, idx, bf) + hv;   // raw residual row slice
  }
}

// ---- eout8: rownorm(xa)->B + e_out + atomic column partials -> ST1 --------
// GRID 512, BLOCK 512 (8 waves): 8 rows/block, wave w owns row gid*8+w.
__global__ __launch_bounds__(512) void eout8_kernel(float* ws, void* dout,
                                                    const int* flagp) {
  const int bf = *flagp;
  int t = threadIdx.x;
  int gid = blockIdx.x;                // 0..511
  int b = gid >> 7;
  long r0 = (long)gid * 8;
  int w = t >> 6, lane = t & 63;
  __shared__ __align__(16) float s2s[8][1026];   // 32.8 KB
  __shared__ __align__(16) float Brow[8][260];   // 8.3 KB
  for (int i = t; i < 8192; i += 512) {
    int h = i >> 10, m = i & 1023;
    s2s[h][m] = ws[S2_OFF + h*4096 + b*1024 + m];
  }
  // ---- rownorm (ddof=1) of raw xa row r0+w, wave-local --------------------
  long row = r0 + w;
  float vals[4];
  float s = 0.0f;
  #pragma unroll
  for (int j = 0; j < 4; ++j) {
    vals[j] = ws[C_OFF + row*256 + lane + 64*j];
    s += vals[j];
  }
  #pragma unroll
  for (int off = 32; off > 0; off >>= 1) s += __shfl_xor(s, off);
  float mean = s * (1.0f/256.0f);
  float ss = 0.0f;
  #pragma unroll
  for (int j = 0; j < 4; ++j) { float d = vals[j] - mean; ss += d*d; }
  #pragma unroll
  for (int off = 32; off > 0; off >>= 1) ss += __shfl_xor(ss, off);
  float inv = 1.0f / (sqrtf(ss * (1.0f/255.0f)) + 1e-6f);
  #pragma unroll
  for (int j = 0; j < 4; ++j) {
    float nv = (vals[j] - mean) * inv;
    ws[B_OFF + row*256 + lane + 64*j] = nv;
    Brow[w][lane + 64*j] = nv;
  }
  __syncthreads();          // s2s staged + Brow complete
  // ---- e_out for row r0+w --------------------------------------------------
  const unsigned long long* prow =
      (const unsigned long long*)(ws + PK_OFF) + row*16;
  float s1v[8], mxv[8], rsv[8];
  #pragma unroll
  for (int h = 0; h < 8; ++h) {
    s1v[h] = ws[S1_OFF + h*4096 + row];
    mxv[h] = ws[MX_OFF + h*4096 + row];
    rsv[h] = ws[RS_OFF + h*4096 + row];
  }
  #pragma unroll
  for (int j = 0; j < 16; ++j) {
    int m = lane + 64*j;
    bool a = (prow[j] >> lane) & 1ull;
    float acc = 0.0f;
    #pragma unroll
    for (int h = 0; h < 8; ++h) {
      float ev = s1v[h] + s2s[h][m];
      ev = (ev >= 0.0f) ? ev : 0.1f*ev;
      ev = a ? ev : NEGC;
      acc += rsv[h] * __expf(ev - mxv[h]);
    }
    stout(dout, 1048576L + row*1024 + m, 0.125f*acc, bf);
  }
  // ---- column partials -> raw ST1 accumulators ----------------------------
  if (t < 256) {
    float ps = 0, pss = 0;
    #pragma unroll
    for (int r = 0; r < 8; ++r) { float v = Brow[r][t]; ps += v; pss += v*v; }
    atomicAdd(&ws[ST1_OFF + b*256 + t], ps);
    atomicAdd(&ws[ST1_OFF + 1024 + b*256 + t], pss);
  }
}

// ---------------- MFMA row-GEMM, fp32-accurate via bf16 hi/lo split --------
// out[row][o] = sum_e in[row][e] * W[o][e] + bias[o];  in = hi + lo (bf16).
// Block 512 thr (8 waves), 16 rows staged in LDS (bf16 hi/lo, pad 264).
// CS=2: grid 512 = 256 rowgroups x 2 colhalves. CS=1: grid 256 (RN-able).
// IN_MODE 0: d_in flat; 1: fp32 + colnorm from RAW sums/sumsq in st
//   (mean/inv computed inline); 2: src permuted; 3: fp32 head-major.
// OUTM 0 fp32 flat (RN=1: fused rownorm + atomic raw ST2 partials -> csout);
//   1: d_out; 4: bf16 T hm; 5: DUAL Q/K.  SOP=1: s1/s2 head reductions.
template<int IN_MODE, int RN, int OUTM, int CS, int SOP>
__global__ __launch_bounds__(512) void gemm2_kernel(const void* inp,
    const unsigned short* wmat, const unsigned short* wmat2,
    const float* bias, const float* bias2, const float* st,
    void* outp, float* csout, const int* flagp) {
  const int bf = *flagp;
  int t = threadIdx.x;
  int gid = blockIdx.x;
  int rowg = (CS == 2) ? (gid >> 1) : gid;
  int colbase = (CS == 2) ? ((gid & 1) * 128) : 0;
  int r0 = rowg * 16;
  __shared__ __align__(16) unsigned short Usm[2*16*264];    // 16.9 KB
  unsigned short (*Uh)[264] = (unsigned short (*)[264])Usm;
  unsigned short (*Ul)[264] = (unsigned short (*)[264])(Usm + 16*264);
  // ---- stage 16 rows as bf16 hi/lo ----------------------------------------
  {
    int srow = t >> 5;
    int e0 = (t & 31) * 8;
    long grow = r0 + srow;
    float v[8];
    if (IN_MODE == 0) {
      #pragma unroll
      for (int j = 0; j < 8; ++j) v[j] = ldin(inp, grow*256 + e0 + j, bf);
    } else if (IN_MODE == 1) {
      int b = (int)(grow >> 10);
      const float* ip = (const float*)inp + grow*256 + e0;
      const float* sp_ = st + b*256 + e0;
      const float* qp_ = st + 1024 + b*256 + e0;
      #pragma unroll
      for (int j = 0; j < 8; ++j) {
        float sm = sp_[j], sq = qp_[j];
        float mean = sm * (1.0f/1024.0f);
        float var = fmaxf((sq - sm*mean) * (1.0f/1023.0f), 0.0f);
        float inv = 1.0f / (sqrtf(var) + 1e-6f);
        v[j] = (ip[j] - mean) * inv;
      }
    } else if (IN_MODE == 2) {
      int b = (int)(grow >> 10), n = (int)(grow & 1023);
      #pragma unroll
      for (int j = 0; j < 8; ++j)
        v[j] = ldin(inp, (long)(n*4 + b)*256 + e0 + j, bf);
    } else {
      int b = (int)(grow >> 10), n = (int)(grow & 1023);
      const float* ip = (const float*)inp
          + ((long)(b*8 + (e0 >> 5))*1024 + n)*32 + (e0 & 31);
      #pragma unroll
      for (int j = 0; j < 8; ++j) v[j] = ip[j];
    }
    unsigned short hv[8], lv[8];
    #pragma unroll
    for (int j = 0; j < 8; ++j) {
      hv[j] = f2bf(v[j]);
      lv[j] = f2bf(v[j] - bf2f(hv[j]));
    }
    *(bf16x8s*)&Uh[srow][e0] = *(bf16x8s*)hv;
    *(bf16x8s*)&Ul[srow][e0] = *(bf16x8s*)lv;
  }
  __syncthreads();
  int w = t >> 6, lane = t & 63, m = lane & 15, quad = lane >> 4;
  const int NT = (CS == 1) ? 2 : 1;
  f32x4 accs[2];
  f32x4 acck;
  #pragma unroll
  for (int nt = 0; nt < NT; ++nt) {
    int o = colbase + w*16 + nt*128 + m;
    const unsigned short* wp = wmat + o*256 + quad*8;
    f32x4 ah_acc = {0,0,0,0}, al_acc = {0,0,0,0};
    f32x4 kh_acc = {0,0,0,0}, kl_acc = {0,0,0,0};
    const unsigned short* wp2 = (OUTM == 5) ? (wmat2 + o*256 + quad*8) : wp;
    #pragma unroll
    for (int kt = 0; kt < 8; ++kt) {
      bf16x8s ah = *(const bf16x8s*)&Uh[m][kt*32 + quad*8];
      bf16x8s al = *(const bf16x8s*)&Ul[m][kt*32 + quad*8];
      bf16x8s bw = *(const bf16x8s*)(wp + kt*32);
      ah_acc = __builtin_amdgcn_mfma_f32_16x16x32_bf16(ah, bw, ah_acc, 0, 0, 0);
      al_acc = __builtin_amdgcn_mfma_f32_16x16x32_bf16(al, bw, al_acc, 0, 0, 0);
      if (OUTM == 5) {
        bf16x8s bw2 = *(const bf16x8s*)(wp2 + kt*32);
        kh_acc = __builtin_amdgcn_mfma_f32_16x16x32_bf16(ah, bw2, kh_acc, 0, 0, 0);
        kl_acc = __builtin_amdgcn_mfma_f32_16x16x32_bf16(al, bw2, kl_acc, 0, 0, 0);
      }
    }
    accs[nt] = ah_acc + al_acc;
    if (OUTM == 5) acck = kh_acc + kl_acc;
    if (RN == 0) {
      float bv = bias[o];
      if constexpr (OUTM == 0) {
        #pragma unroll
        for (int i = 0; i < 4; ++i) {
          long row = r0 + quad*4 + i;
          ((float*)outp)[row*256 + o] = accs[nt][i] + bv;
        }
      } else if constexpr (OUTM == 1) {
        #pragma unroll
        for (int i = 0; i < 4; ++i) {
          long row = r0 + quad*4 + i;
          stout(outp, row*256 + o, accs[nt][i] + bv, bf);
        }
      } else if constexpr (OUTM == 4) {
        int h = o >> 5, d = o & 31;
        #pragma unroll
        for (int i = 0; i < 4; ++i) {
          long row = r0 + quad*4 + i;
          int b = (int)(row >> 10), n = (int)(row & 1023);
          ((unsigned short*)outp)[((long)((b*8 + h)*32 + d))*1024 + n]
              = f2bf(accs[nt][i] + bv);
        }
      } else if constexpr (OUTM == 5) {
        float* wsf = (float*)outp;                 // outp = ws base
        float* qhm = wsf + A_OFF;
        unsigned short* khm = (unsigned short*)(wsf + B_OFF);
        float bq = bias[o], bk = bias2[o];
        int h = o >> 5, d = o & 31;
        #pragma unroll
        for (int i = 0; i < 4; ++i) {
          long row = r0 + quad*4 + i;
          int b = (int)(row >> 10), n = (int)(row & 1023);
          long idx = ((long)((b*8 + h)*1024 + n))*32 + d;
          qhm[idx] = accs[nt][i] + bq;
          khm[idx] = f2bf(acck[i] + bk);
        }
      }
    }
  }
  if constexpr (SOP == 1) {
    // s1/s2 head reductions from the Wh accumulators (CS=2 -> NT=1).
    __shared__ float sp[2][8][16];
    int o = colbase + w*16 + m;
    float a1v = bias2[o];
    float a2v = st[o];
    #pragma unroll
    for (int i = 0; i < 4; ++i) {
      float v1 = accs[0][i] * a1v;
      float v2 = accs[0][i] * a2v;
      #pragma unroll
      for (int off = 8; off > 0; off >>= 1) {
        v1 += __shfl_xor(v1, off);
        v2 += __shfl_xor(v2, off);
      }
      if (m == 0) {
        sp[0][w][quad*4 + i] = v1;
        sp[1][w][quad*4 + i] = v2;
      }
    }
    __syncthreads();
    if (t < 128) {
      int which = t >> 6, h2 = (t >> 4) & 3, r = t & 15;
      float v = sp[which][2*h2][r] + sp[which][2*h2 + 1][r];
      long dst = (which ? S2_OFF : S1_OFF)
               + (long)((colbase >> 5) + h2)*4096 + (r0 + r);
      csout[dst] = v;
    }
  }
  if constexpr (RN == 1) {
    // overlay O (fp32 16x264) on Usm; all U reads are done
    __syncthreads();
    float (*O)[264] = (float (*)[264])Usm;
    #pragma unroll
    for (int nt = 0; nt < NT; ++nt) {
      int oc = colbase + w*16 + nt*128 + m;
      float bv = bias[oc];
      #pragma unroll
      for (int i = 0; i < 4; ++i)
        O[quad*4 + i][oc] = accs[nt][i] + bv;
    }
    __syncthreads();
    #pragma unroll
    for (int rr = 0; rr < 2; ++rr) {
      int r = 2*w + rr;
      float vals[4]; float s = 0.0f;
      #pragma unroll
      for (int j = 0; j < 4; ++j) { vals[j] = O[r][lane + 64*j]; s += vals[j]; }
      #pragma unroll
      for (int off = 32; off > 0; off >>= 1) s += __shfl_xor(s, off);
      float mean = s * (1.0f/256.0f);
      float ss = 0.0f;
      #pragma unroll
      for (int j = 0; j < 4; ++j) { float d = vals[j] - mean; ss += d*d; }
      #pragma unroll
      for (int off = 32; off > 0; off >>= 1) ss += __shfl_xor(ss, off);
      float inv = 1.0f / (sqrtf(ss * (1.0f/255.0f)) + 1e-6f);
      #pragma unroll
      for (int j = 0; j < 4; ++j) {
        float nv = (vals[j] - mean) * inv;
        ((float*)outp)[(long)(r0 + r)*256 + lane + 64*j] = nv;
        O[r][lane + 64*j] = nv;      // write back for column partials
      }
    }
    __syncthreads();
    if (csout != nullptr && t < 256) {
      int b = r0 >> 10;
      float s = 0, ss = 0;
      #pragma unroll
      for (int r = 0; r < 16; ++r) { float v = O[r][t]; s += v; ss += v*v; }
      atomicAdd(&csout[b*256 + t], s);          // raw ST2 sums
      atomicAdd(&csout[1024 + b*256 + t], ss);
    }
  }
}

// -------- MHA via MFMA, flash-register softmax, 16 q-rows per block --------
// GRID 2048, BLOCK 512 (8 waves): 64 row-groups x 4 b x 8 h (h low 3 bits).
// QK into registers; per-wave partial max/sum + 16-thread combine; waves
// write normalized bf16 P directly.  LDS ~44 KB -> 3 blocks/CU.
#define P2S 1036
__global__ __launch_bounds__(512) void attn2_kernel(float* ws) {
  int t = threadIdx.x;
  int gid = blockIdx.x;
  int h = gid & 7;
  int b = (gid >> 3) & 3;
  int n0 = (gid >> 5) << 4;   // 16 q-rows per block; gid>>5 in 0..63
  __shared__ __align__(16) unsigned short P[16][P2S];   // 33.2 KB
  __shared__ float pmx[8][16];
  __shared__ float psm[8][16];
  __shared__ float gmx[16];
  __shared__ float grs[16];
  __shared__ __align__(16) float opart[8][16][17];      // 8.7 KB
  float* qq = ws + A_OFF;
  const unsigned short* kk = (const unsigned short*)(ws + B_OFF);
  const unsigned short* vt = (const unsigned short*)(ws + C_OFF);
  int base_bh = (b*8 + h)*1024;
  int w = t >> 6, lane = t & 63;   // w 0..7
  int m = lane & 15, quad = lane >> 4;
  const float scl = 0.17677669529663687f; // 1/sqrt(32)
  float s[8][4];
  // ---- QK via MFMA into registers: wave w covers keys w*128 .. +127 -------
  {
    const float* qp = qq + (base_bh + n0 + m)*32 + quad*8;   // 16 real rows
    bf16x8s aq;
    #pragma unroll
    for (int j = 0; j < 8; ++j) ((unsigned short*)&aq)[j] = f2bf(qp[j]);
    f32x4 zero = {0.0f, 0.0f, 0.0f, 0.0f};
    #pragma unroll
    for (int kt = 0; kt < 8; ++kt) {
      int kbase = w*128 + kt*16;
      bf16x8s bk = *(const bf16x8s*)(kk + (base_bh + kbase + m)*32 + quad*8);
      f32x4 d = __builtin_amdgcn_mfma_f32_16x16x32_bf16(aq, bk, zero, 0, 0, 0);
      #pragma unroll
      for (int i = 0; i < 4; ++i) s[kt][i] = d[i] * scl;
    }
  }
  // ---- per-wave partial max/sum over its 128 keys -------------------------
  #pragma unroll
  for (int i = 0; i < 4; ++i) {
    float mx = s[0][i];
    #pragma unroll
    for (int kt = 1; kt < 8; ++kt) mx = fmaxf(mx, s[kt][i]);
    #pragma unroll
    for (int off = 8; off > 0; off >>= 1) mx = fmaxf(mx, __shfl_xor(mx, off));
    float sm = 0.0f;
    #pragma unroll
    for (int kt = 0; kt < 8; ++kt) sm += __expf(s[kt][i] - mx);
    #pragma unroll
    for (int off = 8; off > 0; off >>= 1) sm += __shfl_xor(sm, off);
    if (m == 0) { pmx[w][quad*4 + i] = mx; psm[w][quad*4 + i] = sm; }
  }
  __syncthreads();
  if (t < 16) {
    float mx = pmx[0][t];
    #pragma unroll
    for (int w2 = 1; w2 < 8; ++w2) mx = fmaxf(mx, pmx[w2][t]);
    float den = 0.0f;
    #pragma unroll
    for (int w2 = 0; w2 < 8; ++w2) den += psm[w2][t] * __expf(pmx[w2][t] - mx);
    gmx[t] = mx;
    grs[t] = 1.0f / den;
  }
  __syncthreads();
  // ---- write normalized P bf16 --------------------------------------------
  #pragma unroll
  for (int i = 0; i < 4; ++i) {
    int row = quad*4 + i;
    float mx = gmx[row], rs = grs[row];
    #pragma unroll
    for (int kt = 0; kt < 8; ++kt)
      P[row][w*128 + kt*16 + m] = f2bf(__expf(s[kt][i] - mx) * rs);
  }
  __syncthreads();
  // ---- PV via MFMA: wave w -> d-tile (w&1), key-chunks (w>>1)*8 .. +7 -----
  {
    int ntile = w & 1;
    int ktbase = (w >> 1) * 8;
    int vd = ntile*16 + m;
    const unsigned short* vrow = vt + base_bh*32 + vd*1024;
    const unsigned short* P0 = &P[m][0];                 // A-frag row m
    f32x4 acc0 = {0.0f, 0.0f, 0.0f, 0.0f};
    f32x4 acc1 = {0.0f, 0.0f, 0.0f, 0.0f};
    #pragma unroll
    for (int kt2 = 0; kt2 < 4; ++kt2) {
      int kt = ktbase + 2*kt2;
      bf16x8s ap0 = *(const bf16x8s*)(P0 + kt*32 + quad*8);
      bf16x8s bv0 = *(const bf16x8s*)(vrow + kt*32 + quad*8);
      acc0 = __builtin_amdgcn_mfma_f32_16x16x32_bf16(ap0, bv0, acc0, 0, 0, 0);
      bf16x8s ap1 = *(const bf16x8s*)(P0 + (kt+1)*32 + quad*8);
      bf16x8s bv1 = *(const bf16x8s*)(vrow + (kt+1)*32 + quad*8);
      acc1 = __builtin_amdgcn_mfma_f32_16x16x32_bf16(ap1, bv1, acc1, 0, 0, 0);
    }
    f32x4 acc = acc0 + acc1;
    #pragma unroll
    for (int i = 0; i < 4; ++i)
      opart[w][quad*4 + i][m] = acc[i];
  }
  __syncthreads();
  {
    int r = t >> 5, d = t & 31;         // 512 threads: 16 rows x 32 d
    int nt = d >> 4, c = d & 15;
    float sum = opart[nt][r][c] + opart[nt + 2][r][c]
              + opart[nt + 4][r][c] + opart[nt + 6][r][c];
    qq[(base_bh + n0 + r)*32 + d] = sum;   // o over q (own slots)
  }
}

extern "C" void kernel_launch(void* const* d_in, const int* in_sizes, int n_in,
                              void* d_out, int out_size, void* d_ws, size_t ws_size,
                              hipStream_t stream) {
  const void* x   = d_in[0];
  const void* src = d_in[1];
  const int* adj  = (const int*)d_in[2];
  const void* wg  = d_in[3];
  const void* a1  = d_in[4];
  const void* a2  = d_in[5];
  const void* lw  = d_in[6];
  const void* lb  = d_in[7];
  const void* ipw = d_in[8];
  const void* ipb = d_in[9];
  const void* opw = d_in[10];
  const void* opb = d_in[11];
  float* ws = (float*)d_ws;
  const unsigned short* wbf = (const unsigned short*)d_ws;
  int* flagp = (int*)(ws + FLAG_F);

  setup_kernel<<<dim3(256, 8), 256, 0, stream>>>(x, wg, lw, ipw, opw, lb, ipb,
      opb, a1, a2, adj, ws, flagp);                        // weights+bias+adj+zero
  gemm2_kernel<0,0,4,2,1><<<512, 512, 0, stream>>>(x, wbf + 0*65536,
      nullptr, ws + CS_OFF + 4096, ws + BIAS_OFF + 1280, ws + BIAS_OFF + 1536,
      ws + A_OFF, ws, flagp);                              // WhT -> A; s1/s2
  attn1a_kernel<<<1024, 512, 0, stream>>>(x, ws, flagp);   // xa -> C, mx/rs
  eout8_kernel<<<512, 512, 0, stream>>>(ws, d_out, flagp); // e_out; rownorm -> B; ST1
  gemm2_kernel<1,1,0,1,0><<<256, 512, 0, stream>>>(ws + B_OFF, wbf + 1*65536,
      nullptr, ws + BIAS_OFF, nullptr, ws + ST1_OFF, ws + C_OFF, ws + ST2_OFF,
      flagp);                                              // lin+RN -> C; ST2
  gemm2_kernel<1,0,5,2,0><<<512, 512, 0, stream>>>(ws + C_OFF, wbf + 2*65536,
      wbf + 3*65536, ws + BIAS_OFF + 256, ws + BIAS_OFF + 512, ws + ST2_OFF,
      ws, nullptr, flagp);                                 // Q -> A, K -> B
  gemm2_kernel<2,0,4,2,0><<<512, 512, 0, stream>>>(src, wbf + 4*65536,
      nullptr, ws + BIAS_OFF + 768, nullptr, nullptr, ws + C_OFF, nullptr,
      flagp);                                              // V^T -> C
  attn2_kernel<<<2048, 512, 0, stream>>>(ws);              // o -> A_OFF
  gemm2_kernel<3,0,1,2,0><<<512, 512, 0, stream>>>(ws + A_OFF, wbf + 5*65536,
      nullptr, ws + BIAS_OFF + 1024, nullptr, nullptr, d_out, nullptr,
      flagp);                                              // out-proj
}